// Round 3
// baseline (323.382 us; speedup 1.0000x reference)
//
#include <hip/hip_runtime.h>
#include <hip/hip_bf16.h>

// Problem constants (T=1024, S=128, H=512)
#define TT 1024
#define SS 128
#define HH 512
#define LN_EPS 1e-5f

typedef float f32x4 __attribute__((ext_vector_type(4)));

// ---------------------------------------------------------------------------
// Kernel 1: projections.
//   blockIdx.z < 4 : text GEMM split-K chunk z:  P[z][m][n] = sum_{k in chunk} text[m,k]*gate_w[n,k]
//   blockIdx.z == 4: struct GEMM (full K):       gsb[s][n]  = sum_k struct[s,k]*gate_w[n,512+k]
// Tile: BM=BN=64, BK=16, 256 threads, 4x4 micro-tile per thread.
// ---------------------------------------------------------------------------
__global__ __launch_bounds__(256) void proj_gemm(
    const float* __restrict__ text, const float* __restrict__ structe,
    const float* __restrict__ gate_w, float* __restrict__ P,
    float* __restrict__ gsb)
{
    const int bz = blockIdx.z;
    const int bm = blockIdx.x;
    const int bn = blockIdx.y;

    const float* A;
    int off, k_begin, k_len;
    float* C;
    if (bz < 4) {
        A = text + bm * 64 * HH;
        off = 0;
        k_begin = bz * 128;
        k_len = 128;
        C = P + (size_t)bz * (TT * HH) + bm * 64 * HH + bn * 64;
    } else {
        if (bm >= 2) return;               // struct has only 128 rows -> 2 tiles
        A = structe + bm * 64 * HH;
        off = HH;
        k_begin = 0;
        k_len = HH;
        C = gsb + bm * 64 * HH + bn * 64;
    }
    const int n_base = bn * 64;

    __shared__ float As[16][68];  // k-major, +4 pad
    __shared__ float Bs[16][68];

    const int tid  = threadIdx.x;
    const int lrow = tid >> 2;   // 0..63
    const int lc   = tid & 3;    // 0..3  (k-chunk of 4)
    const int ty   = tid >> 4;   // 0..15
    const int tx   = tid & 15;   // 0..15

    float acc[4][4] = {};

    const float* a_ptr = A + lrow * HH + k_begin + lc * 4;
    const float* b_ptr = gate_w + (size_t)(n_base + lrow) * (2 * HH) + off + k_begin + lc * 4;

    for (int k = 0; k < k_len; k += 16) {
        float4 av = *(const float4*)a_ptr;  a_ptr += 16;
        float4 bv = *(const float4*)b_ptr;  b_ptr += 16;
        __syncthreads();   // previous iteration's compute done before overwrite
        As[lc * 4 + 0][lrow] = av.x; As[lc * 4 + 1][lrow] = av.y;
        As[lc * 4 + 2][lrow] = av.z; As[lc * 4 + 3][lrow] = av.w;
        Bs[lc * 4 + 0][lrow] = bv.x; Bs[lc * 4 + 1][lrow] = bv.y;
        Bs[lc * 4 + 2][lrow] = bv.z; Bs[lc * 4 + 3][lrow] = bv.w;
        __syncthreads();
        #pragma unroll
        for (int kk = 0; kk < 16; ++kk) {
            float4 a4 = *(const float4*)&As[kk][ty * 4];
            float4 b4 = *(const float4*)&Bs[kk][tx * 4];
            float a[4] = {a4.x, a4.y, a4.z, a4.w};
            float b[4] = {b4.x, b4.y, b4.z, b4.w};
            #pragma unroll
            for (int i = 0; i < 4; ++i)
                #pragma unroll
                for (int j = 0; j < 4; ++j)
                    acc[i][j] = fmaf(a[i], b[j], acc[i][j]);
        }
    }

    #pragma unroll
    for (int i = 0; i < 4; ++i) {
        float4 v = make_float4(acc[i][0], acc[i][1], acc[i][2], acc[i][3]);
        *(float4*)(C + (size_t)(ty * 4 + i) * HH + tx * 4) = v;
    }
}

// ---------------------------------------------------------------------------
// Kernel 2: per-t fused gates + enrichment + layernorm.
// Block = 256 threads: lane h4 = (tid&127)*4 covers H via float4,
// sgroup = tid>>7 splits the s range in half.
// ---------------------------------------------------------------------------
__global__ __launch_bounds__(256) void fuse_k(
    const float* __restrict__ text, const float* __restrict__ structe,
    const int* __restrict__ mask, const float* __restrict__ gate_b,
    const float* __restrict__ P, const float* __restrict__ gsb,
    const float* __restrict__ gamma, const float* __restrict__ beta,
    float* __restrict__ enriched, float* __restrict__ gates)
{
    const int t   = blockIdx.x;
    const int tid = threadIdx.x;
    const int lh  = tid & 127;
    const int sg  = tid >> 7;
    const int h4  = lh * 4;

    // gt[t, h4..h4+3] = sum of 4 K-partials + gate bias
    float4 p0 = *(const float4*)(P + (size_t)0 * TT * HH + (size_t)t * HH + h4);
    float4 p1 = *(const float4*)(P + (size_t)1 * TT * HH + (size_t)t * HH + h4);
    float4 p2 = *(const float4*)(P + (size_t)2 * TT * HH + (size_t)t * HH + h4);
    float4 p3 = *(const float4*)(P + (size_t)3 * TT * HH + (size_t)t * HH + h4);
    float4 gb = *(const float4*)(gate_b + h4);
    float4 gt4;
    gt4.x = p0.x + p1.x + p2.x + p3.x + gb.x;
    gt4.y = p0.y + p1.y + p2.y + p3.y + gb.y;
    gt4.z = p0.z + p1.z + p2.z + p3.z + gb.z;
    gt4.w = p0.w + p1.w + p2.w + p3.w + gb.w;

    float4 acc = make_float4(0.f, 0.f, 0.f, 0.f);
    const int s_begin = sg * 64;

    for (int si = 0; si < 64; ++si) {
        const int s = s_begin + si;
        float4 gs4 = *(const float4*)(gsb + (size_t)s * HH + h4);
        float4 sv  = *(const float4*)(structe + (size_t)s * HH + h4);
        const float mk = (float)mask[t * SS + s];
        f32x4 g;
        g.x = fmaxf(gt4.x + gs4.x, 0.f) * mk;
        g.y = fmaxf(gt4.y + gs4.y, 0.f) * mk;
        g.z = fmaxf(gt4.z + gs4.z, 0.f) * mk;
        g.w = fmaxf(gt4.w + gs4.w, 0.f) * mk;
        f32x4* gp = (f32x4*)(gates + ((size_t)(t * SS + s)) * HH + h4);
        __builtin_nontemporal_store(g, gp);
        acc.x = fmaf(g.x, sv.x, acc.x);
        acc.y = fmaf(g.y, sv.y, acc.y);
        acc.z = fmaf(g.z, sv.z, acc.z);
        acc.w = fmaf(g.w, sv.w, acc.w);
    }

    __shared__ float accs[HH];
    if (sg) *(float4*)&accs[h4] = acc;
    __syncthreads();

    float x0 = 0.f, x1 = 0.f, x2 = 0.f, x3 = 0.f;
    float s1 = 0.f, s2 = 0.f;
    if (!sg) {
        float4 o  = *(float4*)&accs[h4];
        float4 tv = *(const float4*)(text + (size_t)t * HH + h4);
        x0 = tv.x + acc.x + o.x;
        x1 = tv.y + acc.y + o.y;
        x2 = tv.z + acc.z + o.z;
        x3 = tv.w + acc.w + o.w;
        s1 = x0 + x1 + x2 + x3;
        s2 = x0 * x0 + x1 * x1 + x2 * x2 + x3 * x3;
    }
    #pragma unroll
    for (int o = 32; o; o >>= 1) {
        s1 += __shfl_down(s1, o);
        s2 += __shfl_down(s2, o);
    }
    __shared__ float red[8];
    if ((tid & 63) == 0) { red[tid >> 6] = s1; red[4 + (tid >> 6)] = s2; }
    __syncthreads();
    const float sum = red[0] + red[1] + red[2] + red[3];
    const float ssq = red[4] + red[5] + red[6] + red[7];
    const float mu   = sum * (1.0f / HH);
    const float var  = ssq * (1.0f / HH) - mu * mu;
    const float rstd = rsqrtf(var + LN_EPS);

    if (!sg) {
        float4 gm = *(const float4*)(gamma + h4);
        float4 bt = *(const float4*)(beta + h4);
        float4 o;
        o.x = (x0 - mu) * rstd * gm.x + bt.x;
        o.y = (x1 - mu) * rstd * gm.y + bt.y;
        o.z = (x2 - mu) * rstd * gm.z + bt.z;
        o.w = (x3 - mu) * rstd * gm.w + bt.w;
        *(float4*)(enriched + (size_t)t * HH + h4) = o;
    }
}

extern "C" void kernel_launch(void* const* d_in, const int* in_sizes, int n_in,
                              void* d_out, int out_size, void* d_ws, size_t ws_size,
                              hipStream_t stream) {
    const float* text    = (const float*)d_in[0];
    const float* structe = (const float*)d_in[1];
    const int*   mask    = (const int*)d_in[2];
    const float* gate_w  = (const float*)d_in[3];
    const float* gate_b  = (const float*)d_in[4];
    const float* gamma   = (const float*)d_in[5];
    const float* beta    = (const float*)d_in[6];

    float* out      = (float*)d_out;
    float* enriched = out;                       // (1024, 512)
    float* gates    = out + (size_t)TT * HH;     // (1024, 128, 512)

    float* P   = (float*)d_ws;                   // 4 x 1024 x 512 f32 partials
    float* gsb = P + (size_t)4 * TT * HH;        // 128 x 512 f32

    proj_gemm<<<dim3(16, 8, 5), 256, 0, stream>>>(text, structe, gate_w, P, gsb);
    fuse_k<<<TT, 256, 0, stream>>>(text, structe, mask, gate_b, P, gsb,
                                   gamma, beta, enriched, gates);
}

// Round 4
// 318.035 us; speedup vs baseline: 1.0168x; 1.0168x over previous
//
#include <hip/hip_runtime.h>
#include <hip/hip_bf16.h>

// Problem constants (T=1024, S=128, H=512)
#define TT 1024
#define SS 128
#define HH 512
#define LN_EPS 1e-5f

// ---------------------------------------------------------------------------
// Kernel 1: projections.
//   blockIdx.z < 4 : text GEMM split-K chunk z:  P[z][m][n] = sum_{k in chunk} text[m,k]*gate_w[n,k]
//   blockIdx.z == 4: struct GEMM (full K):       gsb[s][n]  = sum_k struct[s,k]*gate_w[n,512+k]
// Tile: BM=BN=64, BK=16, 256 threads, 4x4 micro-tile per thread.
// ---------------------------------------------------------------------------
__global__ __launch_bounds__(256) void proj_gemm(
    const float* __restrict__ text, const float* __restrict__ structe,
    const float* __restrict__ gate_w, float* __restrict__ P,
    float* __restrict__ gsb)
{
    const int bz = blockIdx.z;
    const int bm = blockIdx.x;
    const int bn = blockIdx.y;

    const float* A;
    int off, k_begin, k_len;
    float* C;
    if (bz < 4) {
        A = text + bm * 64 * HH;
        off = 0;
        k_begin = bz * 128;
        k_len = 128;
        C = P + (size_t)bz * (TT * HH) + bm * 64 * HH + bn * 64;
    } else {
        if (bm >= 2) return;               // struct has only 128 rows -> 2 tiles
        A = structe + bm * 64 * HH;
        off = HH;
        k_begin = 0;
        k_len = HH;
        C = gsb + bm * 64 * HH + bn * 64;
    }
    const int n_base = bn * 64;

    __shared__ float As[16][68];  // k-major, +4 pad
    __shared__ float Bs[16][68];

    const int tid  = threadIdx.x;
    const int lrow = tid >> 2;   // 0..63
    const int lc   = tid & 3;    // 0..3  (k-chunk of 4)
    const int ty   = tid >> 4;   // 0..15
    const int tx   = tid & 15;   // 0..15

    float acc[4][4] = {};

    const float* a_ptr = A + lrow * HH + k_begin + lc * 4;
    const float* b_ptr = gate_w + (size_t)(n_base + lrow) * (2 * HH) + off + k_begin + lc * 4;

    for (int k = 0; k < k_len; k += 16) {
        float4 av = *(const float4*)a_ptr;  a_ptr += 16;
        float4 bv = *(const float4*)b_ptr;  b_ptr += 16;
        __syncthreads();   // previous iteration's compute done before overwrite
        As[lc * 4 + 0][lrow] = av.x; As[lc * 4 + 1][lrow] = av.y;
        As[lc * 4 + 2][lrow] = av.z; As[lc * 4 + 3][lrow] = av.w;
        Bs[lc * 4 + 0][lrow] = bv.x; Bs[lc * 4 + 1][lrow] = bv.y;
        Bs[lc * 4 + 2][lrow] = bv.z; Bs[lc * 4 + 3][lrow] = bv.w;
        __syncthreads();
        #pragma unroll
        for (int kk = 0; kk < 16; ++kk) {
            float4 a4 = *(const float4*)&As[kk][ty * 4];
            float4 b4 = *(const float4*)&Bs[kk][tx * 4];
            float a[4] = {a4.x, a4.y, a4.z, a4.w};
            float b[4] = {b4.x, b4.y, b4.z, b4.w};
            #pragma unroll
            for (int i = 0; i < 4; ++i)
                #pragma unroll
                for (int j = 0; j < 4; ++j)
                    acc[i][j] = fmaf(a[i], b[j], acc[i][j]);
        }
    }

    #pragma unroll
    for (int i = 0; i < 4; ++i) {
        float4 v = make_float4(acc[i][0], acc[i][1], acc[i][2], acc[i][3]);
        *(float4*)(C + (size_t)(ty * 4 + i) * HH + tx * 4) = v;
    }
}

// ---------------------------------------------------------------------------
// Kernel 2: per-t fused gates + enrichment + layernorm.
// Block = 256 threads: lane h4 = (tid&127)*4 covers H via float4,
// sgroup = tid>>7 splits the s range in half.
// Plain (cached) float4 stores for gates — nt hint removed (A/B vs round 3).
// ---------------------------------------------------------------------------
__global__ __launch_bounds__(256) void fuse_k(
    const float* __restrict__ text, const float* __restrict__ structe,
    const int* __restrict__ mask, const float* __restrict__ gate_b,
    const float* __restrict__ P, const float* __restrict__ gsb,
    const float* __restrict__ gamma, const float* __restrict__ beta,
    float* __restrict__ enriched, float* __restrict__ gates)
{
    const int t   = blockIdx.x;
    const int tid = threadIdx.x;
    const int lh  = tid & 127;
    const int sg  = tid >> 7;
    const int h4  = lh * 4;

    __shared__ int msk[SS];
    if (tid < SS) msk[tid] = mask[t * SS + tid];

    // gt[t, h4..h4+3] = sum of 4 K-partials + gate bias
    float4 p0 = *(const float4*)(P + (size_t)0 * TT * HH + (size_t)t * HH + h4);
    float4 p1 = *(const float4*)(P + (size_t)1 * TT * HH + (size_t)t * HH + h4);
    float4 p2 = *(const float4*)(P + (size_t)2 * TT * HH + (size_t)t * HH + h4);
    float4 p3 = *(const float4*)(P + (size_t)3 * TT * HH + (size_t)t * HH + h4);
    float4 gb = *(const float4*)(gate_b + h4);
    float4 gt4;
    gt4.x = p0.x + p1.x + p2.x + p3.x + gb.x;
    gt4.y = p0.y + p1.y + p2.y + p3.y + gb.y;
    gt4.z = p0.z + p1.z + p2.z + p3.z + gb.z;
    gt4.w = p0.w + p1.w + p2.w + p3.w + gb.w;

    __syncthreads();

    float4 acc = make_float4(0.f, 0.f, 0.f, 0.f);
    const int s_begin = sg * 64;

    const float* gs_ptr = gsb     + (size_t)s_begin * HH + h4;
    const float* sv_ptr = structe + (size_t)s_begin * HH + h4;
    float*       g_ptr  = gates + ((size_t)t * SS + s_begin) * HH + h4;

    #pragma unroll 4
    for (int si = 0; si < 64; ++si) {
        float4 gs4 = *(const float4*)gs_ptr;  gs_ptr += HH;
        float4 sv  = *(const float4*)sv_ptr;  sv_ptr += HH;
        const float mk = (float)msk[s_begin + si];
        float4 g;
        g.x = fmaxf(gt4.x + gs4.x, 0.f) * mk;
        g.y = fmaxf(gt4.y + gs4.y, 0.f) * mk;
        g.z = fmaxf(gt4.z + gs4.z, 0.f) * mk;
        g.w = fmaxf(gt4.w + gs4.w, 0.f) * mk;
        *(float4*)g_ptr = g;  g_ptr += HH;
        acc.x = fmaf(g.x, sv.x, acc.x);
        acc.y = fmaf(g.y, sv.y, acc.y);
        acc.z = fmaf(g.z, sv.z, acc.z);
        acc.w = fmaf(g.w, sv.w, acc.w);
    }

    __shared__ float accs[HH];
    if (sg) *(float4*)&accs[h4] = acc;
    __syncthreads();

    float x0 = 0.f, x1 = 0.f, x2 = 0.f, x3 = 0.f;
    float s1 = 0.f, s2 = 0.f;
    if (!sg) {
        float4 o  = *(float4*)&accs[h4];
        float4 tv = *(const float4*)(text + (size_t)t * HH + h4);
        x0 = tv.x + acc.x + o.x;
        x1 = tv.y + acc.y + o.y;
        x2 = tv.z + acc.z + o.z;
        x3 = tv.w + acc.w + o.w;
        s1 = x0 + x1 + x2 + x3;
        s2 = x0 * x0 + x1 * x1 + x2 * x2 + x3 * x3;
    }
    #pragma unroll
    for (int o = 32; o; o >>= 1) {
        s1 += __shfl_down(s1, o);
        s2 += __shfl_down(s2, o);
    }
    __shared__ float red[8];
    if ((tid & 63) == 0) { red[tid >> 6] = s1; red[4 + (tid >> 6)] = s2; }
    __syncthreads();
    const float sum = red[0] + red[1] + red[2] + red[3];
    const float ssq = red[4] + red[5] + red[6] + red[7];
    const float mu   = sum * (1.0f / HH);
    const float var  = ssq * (1.0f / HH) - mu * mu;
    const float rstd = rsqrtf(var + LN_EPS);

    if (!sg) {
        float4 gm = *(const float4*)(gamma + h4);
        float4 bt = *(const float4*)(beta + h4);
        float4 o;
        o.x = (x0 - mu) * rstd * gm.x + bt.x;
        o.y = (x1 - mu) * rstd * gm.y + bt.y;
        o.z = (x2 - mu) * rstd * gm.z + bt.z;
        o.w = (x3 - mu) * rstd * gm.w + bt.w;
        *(float4*)(enriched + (size_t)t * HH + h4) = o;
    }
}

extern "C" void kernel_launch(void* const* d_in, const int* in_sizes, int n_in,
                              void* d_out, int out_size, void* d_ws, size_t ws_size,
                              hipStream_t stream) {
    const float* text    = (const float*)d_in[0];
    const float* structe = (const float*)d_in[1];
    const int*   mask    = (const int*)d_in[2];
    const float* gate_w  = (const float*)d_in[3];
    const float* gate_b  = (const float*)d_in[4];
    const float* gamma   = (const float*)d_in[5];
    const float* beta    = (const float*)d_in[6];

    float* out      = (float*)d_out;
    float* enriched = out;                       // (1024, 512)
    float* gates    = out + (size_t)TT * HH;     // (1024, 128, 512)

    float* P   = (float*)d_ws;                   // 4 x 1024 x 512 f32 partials
    float* gsb = P + (size_t)4 * TT * HH;        // 128 x 512 f32

    proj_gemm<<<dim3(16, 8, 5), 256, 0, stream>>>(text, structe, gate_w, P, gsb);
    fuse_k<<<TT, 256, 0, stream>>>(text, structe, mask, gate_b, P, gsb,
                                   gamma, beta, enriched, gates);
}